// Round 3
// baseline (427.217 us; speedup 1.0000x reference)
//
#include <hip/hip_runtime.h>

#define T_LEN 200
#define C_DIM 64

// tanh via exp, safe for large |x| (exp->inf => rcp->0 => r=1), ~6 VALU ops
__device__ __forceinline__ float tanh_fast(float x) {
    float ax = fabsf(x);
    float t  = __expf(2.0f * ax);
    float r  = 1.0f - 2.0f * __builtin_amdgcn_rcpf(t + 1.0f);
    return copysignf(r, x);
}

// One wave per batch row. Single pass over keys, all in registers:
//   load f4: lane l -> row it*4+(l>>4), channels 4*(l&15).. (perfectly coalesced 1KB/wave)
//   score: 4 FMA + 4-step shfl_xor reduce over the 16-lane group
//   e = exp(tanh(s)) masked; acc4 += e*k4; esum += e   (same registers, no second read)
//   final: shfl_xor 16/32 reduce over the 4 row-groups, lanes 0-15 store out f4.
// No LDS, no barriers -> ~24 waves/CU, pure HBM stream.
__global__ __launch_bounds__(256, 6) void attn_pool_kernel(
    const float* __restrict__ q,     // [B,1,64]
    const float* __restrict__ keys,  // [B,200,64]
    const int*   __restrict__ klen,  // [B,1]
    const float* __restrict__ W,     // [128,1]
    const float* __restrict__ bias,  // [1]
    float* __restrict__ out,         // [B,1,64]
    int B)
{
    const int lane = threadIdx.x & 63;
    const int wave = threadIdx.x >> 6;
    const int b    = blockIdx.x * 4 + wave;
    if (b >= B) return;

    const int slot = lane & 15;   // float4 slot = channels [4*slot, 4*slot+4)
    const int grp  = lane >> 4;   // row offset within a 4-row load group

    const float4* kg = reinterpret_cast<const float4*>(keys) + (size_t)b * (T_LEN * C_DIM / 4);
    const float4  w1 = reinterpret_cast<const float4*>(W)[slot];
    const float4  w2 = reinterpret_cast<const float4*>(W)[16 + slot];
    const int     len = klen[b];

    // qdot = q[b]·W1 + bias (16-lane reduce, replicated across groups)
    float4 q4 = reinterpret_cast<const float4*>(q)[(size_t)b * 16 + slot];
    float qp = q4.x * w1.x + q4.y * w1.y + q4.z * w1.z + q4.w * w1.w;
    qp += __shfl_xor(qp, 1, 64);
    qp += __shfl_xor(qp, 2, 64);
    qp += __shfl_xor(qp, 4, 64);
    qp += __shfl_xor(qp, 8, 64);
    const float qdot = qp + bias[0];

    float4 acc  = make_float4(0.f, 0.f, 0.f, 0.f);
    float  esum = 0.f;

    for (int oo = 0; oo < 10; ++oo) {          // 10 x 5 f4-loads = 50 loads = 200 rows
        float4 k4[5];
        #pragma unroll
        for (int u = 0; u < 5; ++u)
            k4[u] = kg[(oo * 5 + u) * 64 + lane];   // 5 loads in flight
        #pragma unroll
        for (int u = 0; u < 5; ++u) {
            const int t = (oo * 5 + u) * 4 + grp;
            float p = k4[u].x * w2.x + k4[u].y * w2.y + k4[u].z * w2.z + k4[u].w * w2.w;
            p += __shfl_xor(p, 1, 64);
            p += __shfl_xor(p, 2, 64);
            p += __shfl_xor(p, 4, 64);
            p += __shfl_xor(p, 8, 64);              // all 16 lanes hold row-dot
            const float s = tanh_fast(p + qdot);
            const float e = (len == 0) ? 1.0f       // all-masked row -> uniform weights
                          : ((t < len) ? __expf(s) : 0.0f);
            esum += e;
            acc.x = fmaf(e, k4[u].x, acc.x);
            acc.y = fmaf(e, k4[u].y, acc.y);
            acc.z = fmaf(e, k4[u].z, acc.z);
            acc.w = fmaf(e, k4[u].w, acc.w);
        }
    }

    // reduce acc/esum across the 4 row-groups (lanes differing in bits 4-5)
    #pragma unroll
    for (int off = 16; off <= 32; off <<= 1) {
        acc.x += __shfl_xor(acc.x, off, 64);
        acc.y += __shfl_xor(acc.y, off, 64);
        acc.z += __shfl_xor(acc.z, off, 64);
        acc.w += __shfl_xor(acc.w, off, 64);
        esum  += __shfl_xor(esum,  off, 64);
    }

    if (grp == 0) {
        const float inv = 1.0f / esum;
        float4 res = make_float4(acc.x * inv, acc.y * inv, acc.z * inv, acc.w * inv);
        reinterpret_cast<float4*>(out)[(size_t)b * 16 + slot] = res;
    }
}

extern "C" void kernel_launch(void* const* d_in, const int* in_sizes, int n_in,
                              void* d_out, int out_size, void* d_ws, size_t ws_size,
                              hipStream_t stream) {
    const float* q    = (const float*)d_in[0];
    const float* keys = (const float*)d_in[1];
    const int*   klen = (const int*)d_in[2];
    const float* W    = (const float*)d_in[3];
    const float* bias = (const float*)d_in[4];
    float* out = (float*)d_out;
    const int B = in_sizes[0] / C_DIM;   // 4096
    attn_pool_kernel<<<(B + 3) / 4, 256, 0, stream>>>(q, keys, klen, W, bias, out, B);
}